// Round 2
// baseline (1079.415 us; speedup 1.0000x reference)
//
#include <hip/hip_runtime.h>
#include <math.h>

#define N_NODES 160000
#define NODES_PER_GRAPH 20000
#define N_EDGES 5120000
#define HID 16
#define NGRAPH 8
#define OUTC 10

// ---------------- scalar scatter-add over edges --------------------------
// agg[tgt[e]] += ew[e] * xin[src[e]]   (4 edges per thread-iter, vectorized)
__global__ __launch_bounds__(256) void scatter_add(
    const int4* __restrict__ src4, const int4* __restrict__ tgt4,
    const float4* __restrict__ ew4, const float* __restrict__ xin,
    float* __restrict__ agg, int nquads)
{
    int q = blockIdx.x * blockDim.x + threadIdx.x;
    int stride = gridDim.x * blockDim.x;
    for (; q < nquads; q += stride) {
        int4 s = src4[q];
        int4 t = tgt4[q];
        float4 w = ew4[q];
        atomicAdd(&agg[t.x], w.x * xin[s.x]);
        atomicAdd(&agg[t.y], w.y * xin[s.y]);
        atomicAdd(&agg[t.z], w.z * xin[s.z]);
        atomicAdd(&agg[t.w], w.w * xin[s.w]);
    }
}

// ---------------- per-node middle: h1 = relu(conv1); s = Wr2.h1 ; h2init = Ws2.h1 + br2
__global__ __launch_bounds__(256) void node_mid(
    const float* __restrict__ x, const float* __restrict__ agg1,
    const float* __restrict__ Wr1, const float* __restrict__ br1,
    const float* __restrict__ Ws1, const float* __restrict__ Wr2,
    const float* __restrict__ br2, const float* __restrict__ Ws2,
    float* __restrict__ sbuf, float* __restrict__ h2init)
{
    int n = blockIdx.x * blockDim.x + threadIdx.x;
    if (n >= N_NODES) return;
    float a = agg1[n];
    float xi = x[n];
    float sv = 0.f, tv = 0.f;
#pragma unroll
    for (int c = 0; c < HID; ++c) {
        float h = fmaxf(fmaf(a, Wr1[c], fmaf(xi, Ws1[c], br1[c])), 0.f);
        sv = fmaf(Wr2[c], h, sv);
        tv = fmaf(Ws2[c], h, tv);
    }
    sbuf[n] = sv;
    h2init[n] = tv + br2[0];
}

// ---------------- batched GEMV: out[b][o] = relu?(in[b][:] . W[o][:] + bias[o])
// One block computes R consecutive W-rows for all 8 graphs.
template <int IN, int R>
__global__ __launch_bounds__(256) void mlp_layer(
    const float* __restrict__ in,   // [8][IN]
    const float* __restrict__ W,    // [outRows][IN]
    const float* __restrict__ bias, // [outRows]
    float* __restrict__ out,        // [8][outRows]
    int outRows, int do_relu)
{
    constexpr int NV = IN / 4;
    const int o0 = blockIdx.x * R;
    const int tid = threadIdx.x;
    const float4* __restrict__ in4 = (const float4*)in;
    const float4* __restrict__ W4 = (const float4*)W;

    float acc[R][NGRAPH];
#pragma unroll
    for (int r = 0; r < R; ++r)
#pragma unroll
        for (int b = 0; b < NGRAPH; ++b) acc[r][b] = 0.f;

    for (int i = tid; i < NV; i += 256) {
        float4 hv[NGRAPH];
#pragma unroll
        for (int b = 0; b < NGRAPH; ++b) hv[b] = in4[b * NV + i];
#pragma unroll
        for (int r = 0; r < R; ++r) {
            float4 wv = W4[(o0 + r) * NV + i];
#pragma unroll
            for (int b = 0; b < NGRAPH; ++b) {
                acc[r][b] = fmaf(wv.x, hv[b].x, acc[r][b]);
                acc[r][b] = fmaf(wv.y, hv[b].y, acc[r][b]);
                acc[r][b] = fmaf(wv.z, hv[b].z, acc[r][b]);
                acc[r][b] = fmaf(wv.w, hv[b].w, acc[r][b]);
            }
        }
    }

    __shared__ float red[4][R * NGRAPH];
    const int lane = tid & 63;
    const int wave = tid >> 6;
#pragma unroll
    for (int r = 0; r < R; ++r)
#pragma unroll
        for (int b = 0; b < NGRAPH; ++b) {
            float v = acc[r][b];
#pragma unroll
            for (int off = 32; off > 0; off >>= 1) v += __shfl_down(v, off, 64);
            if (lane == 0) red[wave][r * NGRAPH + b] = v;
        }
    __syncthreads();
    if (tid < R * NGRAPH) {
        int r = tid / NGRAPH;
        int b = tid % NGRAPH;
        float v = red[0][tid] + red[1][tid] + red[2][tid] + red[3][tid];
        v += bias[o0 + r];
        if (do_relu) v = fmaxf(v, 0.f);
        out[b * outRows + o0 + r] = v;
    }
}

// ---------------- final linear (160 -> 10) + log_softmax, one wave per graph
__global__ __launch_bounds__(64) void head_kernel(
    const float* __restrict__ g3,  // [8][160]
    const float* __restrict__ W4,  // [10][160]
    const float* __restrict__ b4,  // [10]
    float* __restrict__ out)       // [8][10]
{
    const int b = blockIdx.x;
    const int l = threadIdx.x;
    float acc[OUTC];
#pragma unroll
    for (int o = 0; o < OUTC; ++o) acc[o] = 0.f;
    for (int i = l; i < 160; i += 64) {
        float gv = g3[b * 160 + i];
#pragma unroll
        for (int o = 0; o < OUTC; ++o) acc[o] = fmaf(gv, W4[o * 160 + i], acc[o]);
    }
#pragma unroll
    for (int o = 0; o < OUTC; ++o) {
#pragma unroll
        for (int off = 32; off > 0; off >>= 1) acc[o] += __shfl_down(acc[o], off, 64);
    }
    if (l == 0) {
        float z[OUTC];
        float m = -INFINITY;
#pragma unroll
        for (int o = 0; o < OUTC; ++o) {
            z[o] = acc[o] + b4[o];
            m = fmaxf(m, z[o]);
        }
        float sum = 0.f;
#pragma unroll
        for (int o = 0; o < OUTC; ++o) sum += expf(z[o] - m);
        float lse = logf(sum);
#pragma unroll
        for (int o = 0; o < OUTC; ++o) out[b * OUTC + o] = z[o] - m - lse;
    }
}

extern "C" void kernel_launch(void* const* d_in, const int* in_sizes, int n_in,
                              void* d_out, int out_size, void* d_ws, size_t ws_size,
                              hipStream_t stream)
{
    const float* x   = (const float*)d_in[0];
    const float* ew  = (const float*)d_in[1];
    const float* Wr1 = (const float*)d_in[2];
    const float* br1 = (const float*)d_in[3];
    const float* Ws1 = (const float*)d_in[4];
    const float* Wr2 = (const float*)d_in[5];
    const float* br2 = (const float*)d_in[6];
    const float* Ws2 = (const float*)d_in[7];
    const float* W1  = (const float*)d_in[8];
    const float* b1  = (const float*)d_in[9];
    const float* W2  = (const float*)d_in[10];
    const float* b2  = (const float*)d_in[11];
    const float* W3  = (const float*)d_in[12];
    const float* b3  = (const float*)d_in[13];
    const float* W4  = (const float*)d_in[14];
    const float* b4  = (const float*)d_in[15];
    const int*  eidx = (const int*)d_in[16];
    float* out = (float*)d_out;

    float* ws   = (float*)d_ws;
    float* agg1 = ws;               // 160000
    float* sbuf = ws + 160000;      // 160000
    float* h2   = ws + 320000;      // 160000 (seeded with Ws2.h1 + br2, atomics add the rest)
    float* g1   = ws + 480000;      // 8*4000
    float* g2   = ws + 512000;      // 8*800
    float* g3   = ws + 518400;      // 8*160

    hipMemsetAsync(agg1, 0, N_NODES * sizeof(float), stream);

    const int4* src4 = (const int4*)eidx;               // edge_index row 0
    const int4* tgt4 = (const int4*)(eidx + N_EDGES);   // edge_index row 1
    const float4* ew4 = (const float4*)ew;
    const int nquads = N_EDGES / 4;

    scatter_add<<<2048, 256, 0, stream>>>(src4, tgt4, ew4, x, agg1, nquads);
    node_mid<<<(N_NODES + 255) / 256, 256, 0, stream>>>(x, agg1, Wr1, br1, Ws1,
                                                        Wr2, br2, Ws2, sbuf, h2);
    scatter_add<<<2048, 256, 0, stream>>>(src4, tgt4, ew4, sbuf, h2, nquads);

    mlp_layer<20000, 8><<<500, 256, 0, stream>>>(h2, W1, b1, g1, 4000, 1);
    mlp_layer<4000, 8><<<100, 256, 0, stream>>>(g1, W2, b2, g2, 800, 1);
    mlp_layer<800, 8><<<20, 256, 0, stream>>>(g2, W3, b3, g3, 160, 1);
    head_kernel<<<NGRAPH, 64, 0, stream>>>(g3, W4, b4, out);
}

// Round 4
// 778.245 us; speedup vs baseline: 1.3870x; 1.3870x over previous
//
#include <hip/hip_runtime.h>
#include <math.h>

#define N_NODES 160000
#define N_EDGES 5120000
#define HID 16
#define NGRAPH 8
#define OUTC 10

#define NB 16000                 // bins per range-pass (64 KB LDS), NB*RPASS == N_NODES
#define RPASS 10
#define BCHUNK 32                // edge chunks; grid = RPASS*BCHUNK = 320
#define EPB (N_EDGES / BCHUNK)   // 160000 edges per chunk

// ---- LDS-binned scatter: partial[b][lo+i] = sum over edges in chunk b with tgt==lo+i
// No global atomics. blockIdx = r*32 + b so all 10 range-passes of chunk b share an XCD's L2.
__global__ __launch_bounds__(512) void scatter_binned(
    const int* __restrict__ tgt, const int* __restrict__ src,
    const float* __restrict__ ew, const float* __restrict__ xin,
    float* __restrict__ partial)   // [BCHUNK][N_NODES]
{
    __shared__ float bins[NB];
    const int r = blockIdx.x >> 5;
    const int b = blockIdx.x & 31;
    const int lo = r * NB;

    float4* bins4 = (float4*)bins;
    for (int i = threadIdx.x; i < NB / 4; i += 512) bins4[i] = make_float4(0.f, 0.f, 0.f, 0.f);
    __syncthreads();

    const int q0 = b * (EPB / 4);
    const int qend = q0 + EPB / 4;
    const int4* __restrict__ t4 = (const int4*)tgt;
    const int4* __restrict__ s4 = (const int4*)src;
    const float4* __restrict__ w4 = (const float4*)ew;
    for (int q = q0 + threadIdx.x; q < qend; q += 512) {
        int4 t = t4[q];
        int4 s = s4[q];
        float4 w = w4[q];
        unsigned d;
        d = (unsigned)(t.x - lo); if (d < NB) atomicAdd(&bins[d], w.x * xin[s.x]);
        d = (unsigned)(t.y - lo); if (d < NB) atomicAdd(&bins[d], w.y * xin[s.y]);
        d = (unsigned)(t.z - lo); if (d < NB) atomicAdd(&bins[d], w.z * xin[s.z]);
        d = (unsigned)(t.w - lo); if (d < NB) atomicAdd(&bins[d], w.w * xin[s.w]);
    }
    __syncthreads();

    float4* dst = (float4*)(partial + (size_t)b * N_NODES + lo);
    for (int i = threadIdx.x; i < NB / 4; i += 512) dst[i] = bins4[i];
}

// ---- per-node middle: inline 32-way reduce of partial -> agg1;
// h1 = relu(conv1); sbuf = Wr2.h1 ; h2 = Ws2.h1 + br2 (seed; conv2 partials added later)
__global__ __launch_bounds__(256) void node_mid(
    const float4* __restrict__ x4, const float4* __restrict__ partial4, // [BCHUNK][N_NODES/4]
    const float* __restrict__ Wr1, const float* __restrict__ br1,
    const float* __restrict__ Ws1, const float* __restrict__ Wr2,
    const float* __restrict__ br2, const float* __restrict__ Ws2,
    float4* __restrict__ sbuf4, float4* __restrict__ h2_4)
{
    int n4 = blockIdx.x * blockDim.x + threadIdx.x;
    if (n4 >= N_NODES / 4) return;

    float4 a = make_float4(0.f, 0.f, 0.f, 0.f);
#pragma unroll
    for (int b = 0; b < BCHUNK; ++b) {
        float4 p = partial4[b * (N_NODES / 4) + n4];
        a.x += p.x; a.y += p.y; a.z += p.z; a.w += p.w;
    }
    float4 xi = x4[n4];
    float aa[4] = {a.x, a.y, a.z, a.w};
    float xx[4] = {xi.x, xi.y, xi.z, xi.w};
    float sv[4], tv[4];
#pragma unroll
    for (int j = 0; j < 4; ++j) {
        float s = 0.f, t = 0.f;
#pragma unroll
        for (int c = 0; c < HID; ++c) {
            float h = fmaxf(fmaf(aa[j], Wr1[c], fmaf(xx[j], Ws1[c], br1[c])), 0.f);
            s = fmaf(Wr2[c], h, s);
            t = fmaf(Ws2[c], h, t);
        }
        sv[j] = s;
        tv[j] = t + br2[0];
    }
    sbuf4[n4] = make_float4(sv[0], sv[1], sv[2], sv[3]);
    h2_4[n4]  = make_float4(tv[0], tv[1], tv[2], tv[3]);
}

// ---- h2 += sum_b partialB[b]
__global__ __launch_bounds__(256) void reduce_add(
    const float4* __restrict__ partial4, float4* __restrict__ h2_4)
{
    int n4 = blockIdx.x * blockDim.x + threadIdx.x;
    if (n4 >= N_NODES / 4) return;
    float4 a = h2_4[n4];
#pragma unroll
    for (int b = 0; b < BCHUNK; ++b) {
        float4 p = partial4[b * (N_NODES / 4) + n4];
        a.x += p.x; a.y += p.y; a.z += p.z; a.w += p.w;
    }
    h2_4[n4] = a;
}

// ---- batched GEMV: out[b][o] = relu?(in[b][:] . W[o][:] + bias[o])
template <int IN, int R, int THREADS>
__global__ __launch_bounds__(THREADS) void mlp_layer(
    const float* __restrict__ in,   // [8][IN]
    const float* __restrict__ W,    // [outRows][IN]
    const float* __restrict__ bias, // [outRows]
    float* __restrict__ out,        // [8][outRows]
    int outRows, int do_relu)
{
    constexpr int NV = IN / 4;
    constexpr int NWAVE = THREADS / 64;
    const int o0 = blockIdx.x * R;
    const int tid = threadIdx.x;
    const float4* __restrict__ in4 = (const float4*)in;
    const float4* __restrict__ W4 = (const float4*)W;

    float acc[R][NGRAPH];
#pragma unroll
    for (int r = 0; r < R; ++r)
#pragma unroll
        for (int b = 0; b < NGRAPH; ++b) acc[r][b] = 0.f;

    for (int i = tid; i < NV; i += THREADS) {
        float4 hv[NGRAPH];
#pragma unroll
        for (int b = 0; b < NGRAPH; ++b) hv[b] = in4[b * NV + i];
#pragma unroll
        for (int r = 0; r < R; ++r) {
            float4 wv = W4[(o0 + r) * NV + i];
#pragma unroll
            for (int b = 0; b < NGRAPH; ++b) {
                acc[r][b] = fmaf(wv.x, hv[b].x, acc[r][b]);
                acc[r][b] = fmaf(wv.y, hv[b].y, acc[r][b]);
                acc[r][b] = fmaf(wv.z, hv[b].z, acc[r][b]);
                acc[r][b] = fmaf(wv.w, hv[b].w, acc[r][b]);
            }
        }
    }

    __shared__ float red[NWAVE][R * NGRAPH];
    const int lane = tid & 63;
    const int wave = tid >> 6;
#pragma unroll
    for (int r = 0; r < R; ++r)
#pragma unroll
        for (int b = 0; b < NGRAPH; ++b) {
            float v = acc[r][b];
#pragma unroll
            for (int off = 32; off > 0; off >>= 1) v += __shfl_down(v, off, 64);
            if (lane == 0) red[wave][r * NGRAPH + b] = v;
        }
    __syncthreads();
    if (tid < R * NGRAPH) {
        int r = tid / NGRAPH;
        int b = tid % NGRAPH;
        float v = 0.f;
#pragma unroll
        for (int wv = 0; wv < NWAVE; ++wv) v += red[wv][tid];
        v += bias[o0 + r];
        if (do_relu) v = fmaxf(v, 0.f);
        out[b * outRows + o0 + r] = v;
    }
}

// ---- final linear (160 -> 10) + log_softmax, one wave per graph
__global__ __launch_bounds__(64) void head_kernel(
    const float* __restrict__ g3,  // [8][160]
    const float* __restrict__ W4,  // [10][160]
    const float* __restrict__ b4,  // [10]
    float* __restrict__ out)       // [8][10]
{
    const int b = blockIdx.x;
    const int l = threadIdx.x;
    float acc[OUTC];
#pragma unroll
    for (int o = 0; o < OUTC; ++o) acc[o] = 0.f;
    for (int i = l; i < 160; i += 64) {
        float gv = g3[b * 160 + i];
#pragma unroll
        for (int o = 0; o < OUTC; ++o) acc[o] = fmaf(gv, W4[o * 160 + i], acc[o]);
    }
#pragma unroll
    for (int o = 0; o < OUTC; ++o) {
#pragma unroll
        for (int off = 32; off > 0; off >>= 1) acc[o] += __shfl_down(acc[o], off, 64);
    }
    if (l == 0) {
        float z[OUTC];
        float m = -INFINITY;
#pragma unroll
        for (int o = 0; o < OUTC; ++o) {
            z[o] = acc[o] + b4[o];
            m = fmaxf(m, z[o]);
        }
        float sum = 0.f;
#pragma unroll
        for (int o = 0; o < OUTC; ++o) sum += expf(z[o] - m);
        float lse = logf(sum);
#pragma unroll
        for (int o = 0; o < OUTC; ++o) out[b * OUTC + o] = z[o] - m - lse;
    }
}

extern "C" void kernel_launch(void* const* d_in, const int* in_sizes, int n_in,
                              void* d_out, int out_size, void* d_ws, size_t ws_size,
                              hipStream_t stream)
{
    const float* x   = (const float*)d_in[0];
    const float* ew  = (const float*)d_in[1];
    const float* Wr1 = (const float*)d_in[2];
    const float* br1 = (const float*)d_in[3];
    const float* Ws1 = (const float*)d_in[4];
    const float* Wr2 = (const float*)d_in[5];
    const float* br2 = (const float*)d_in[6];
    const float* Ws2 = (const float*)d_in[7];
    const float* W1  = (const float*)d_in[8];
    const float* b1  = (const float*)d_in[9];
    const float* W2  = (const float*)d_in[10];
    const float* b2  = (const float*)d_in[11];
    const float* W3  = (const float*)d_in[12];
    const float* b3  = (const float*)d_in[13];
    const float* W4  = (const float*)d_in[14];
    const float* b4  = (const float*)d_in[15];
    const int*  eidx = (const int*)d_in[16];
    float* out = (float*)d_out;

    const int* src = eidx;             // edge_index row 0
    const int* tgt = eidx + N_EDGES;   // edge_index row 1

    float* ws      = (float*)d_ws;
    float* partial = ws;                      // BCHUNK * N_NODES = 5,120,000 floats (reused)
    float* sbuf    = ws + 5120000;            // 160000
    float* h2      = ws + 5280000;            // 160000
    float* g1      = ws + 5440000;            // 8*4000
    float* g2      = ws + 5472000;            // 8*800
    float* g3      = ws + 5478400;            // 8*160

    // conv1 scatter (no atomics, no memset)
    scatter_binned<<<RPASS * BCHUNK, 512, 0, stream>>>(tgt, src, ew, x, partial);
    node_mid<<<(N_NODES / 4 + 255) / 256, 256, 0, stream>>>(
        (const float4*)x, (const float4*)partial, Wr1, br1, Ws1, Wr2, br2, Ws2,
        (float4*)sbuf, (float4*)h2);
    // conv2 scatter (scalar s = Wr2.h1 per node), reuse partial slab
    scatter_binned<<<RPASS * BCHUNK, 512, 0, stream>>>(tgt, src, ew, sbuf, partial);
    reduce_add<<<(N_NODES / 4 + 255) / 256, 256, 0, stream>>>(
        (const float4*)partial, (float4*)h2);

    mlp_layer<20000, 8, 512><<<500, 512, 0, stream>>>(h2, W1, b1, g1, 4000, 1);
    mlp_layer<4000, 8, 256><<<100, 256, 0, stream>>>(g1, W2, b2, g2, 800, 1);
    mlp_layer<800, 8, 256><<<20, 256, 0, stream>>>(g2, W3, b3, g3, 160, 1);
    head_kernel<<<NGRAPH, 64, 0, stream>>>(g3, W4, b4, out);
}